// Round 5
// baseline (417.603 us; speedup 1.0000x reference)
//
#include <hip/hip_runtime.h>

typedef int v4i __attribute__((ext_vector_type(4)));
typedef int v16i __attribute__((ext_vector_type(16)));

#define BM 256
#define BN 128
#define BKB 64                       // K-bytes per step (i8 elems), 64 B rows
#define SLOT (BM * BKB + BN * BKB)   // 24576 B per ring slot (16K A + 8K B)
#define NRING 3                      // 72 KB/block; 2 blocks/CU = 144 KB <= 160

// async global->LDS, 16B per lane. LDS dest = wave-uniform base + lane*16.
#define GLOAD_LDS(gptr, lptr)                                                         \
  __builtin_amdgcn_global_load_lds(                                                   \
      (const __attribute__((address_space(1))) unsigned int*)(gptr),                  \
      (__attribute__((address_space(3))) unsigned int*)(lptr), 16, 0, 0)

// ---------- preprocessing ----------

__device__ __forceinline__ float max4abs(float4 v) {
  return fmaxf(fmaxf(fabsf(v.x), fabsf(v.y)), fmaxf(fabsf(v.z), fabsf(v.w)));
}

__device__ __forceinline__ int packq4(float4 v, float inv) {
  int b0 = ((int)fminf(127.f, fmaxf(-127.f, rintf(v.x * inv)))) & 255;
  int b1 = ((int)fminf(127.f, fmaxf(-127.f, rintf(v.y * inv)))) & 255;
  int b2 = ((int)fminf(127.f, fmaxf(-127.f, rintf(v.z * inv)))) & 255;
  int b3 = ((int)fminf(127.f, fmaxf(-127.f, rintf(v.w * inv)))) & 255;
  return b0 | (b1 << 8) | (b2 << 16) | (b3 << 24);
}

// Fused: blocks [0,nrows) per-row i8-quantize x; blocks [nrows,nrows+1024) reduce
// max|W|; last block reduces max|b|. All independent -> one dispatch.
__global__ void prep1_kernel(const float4* __restrict__ X4,
                             signed char* __restrict__ Q,
                             float* __restrict__ sx, int K, int nrows,
                             const float4* __restrict__ W4, long nW4,
                             const float4* __restrict__ b4, int nb4,
                             unsigned* __restrict__ mx) {
  __shared__ float sm[4];
  const int tid = threadIdx.x;
  const int bid = blockIdx.x;

  if (bid < nrows) {  // ---- xquant: one block per row, K==4096 assumed
    const float4* xr = X4 + (size_t)bid * (K / 4);
    float4 v0 = xr[tid], v1 = xr[tid + 256], v2 = xr[tid + 512], v3 = xr[tid + 768];
    float m = fmaxf(fmaxf(max4abs(v0), max4abs(v1)), fmaxf(max4abs(v2), max4abs(v3)));
    for (int off = 32; off > 0; off >>= 1) m = fmaxf(m, __shfl_down(m, off));
    if ((tid & 63) == 0) sm[tid >> 6] = m;
    __syncthreads();
    const float total = fmaxf(fmaxf(sm[0], sm[1]), fmaxf(sm[2], sm[3]));
    const float inv = 127.f / total;
    int* qw = (int*)(Q + (size_t)bid * K);
    qw[tid]       = packq4(v0, inv);
    qw[tid + 256] = packq4(v1, inv);
    qw[tid + 512] = packq4(v2, inv);
    qw[tid + 768] = packq4(v3, inv);
    if (tid == 0) sx[bid] = total * (1.f / 127.f);
    return;
  }

  // ---- absmax reductions
  float m = 0.f;
  const bool isB = (bid == gridDim.x - 1);
  if (!isB) {
    const long wb = bid - nrows;           // 0..1023
    const long stride = 1024L * blockDim.x;
    for (long i = wb * blockDim.x + tid; i < nW4; i += stride)
      m = fmaxf(m, max4abs(W4[i]));
  } else {
    for (int i = tid; i < nb4; i += blockDim.x) m = fmaxf(m, max4abs(b4[i]));
  }
  for (int off = 32; off > 0; off >>= 1) m = fmaxf(m, __shfl_down(m, off));
  if ((tid & 63) == 0) sm[tid >> 6] = m;
  __syncthreads();
  if (tid == 0) {
    m = fmaxf(fmaxf(sm[0], sm[1]), fmaxf(sm[2], sm[3]));
    atomicMax(mx + (isB ? 1 : 0), __float_as_uint(m));  // nonneg: uint order == float
  }
}

// Ternarize W -> i8{-1,0,1} (packed dword per float4, coalesced); last block: b -> fp32.
__global__ void prep_w_kernel(const float4* __restrict__ W4, long nW4,
                              const float4* __restrict__ b4, int nb4,
                              const unsigned* __restrict__ mx,
                              const float* __restrict__ bscale,
                              int* __restrict__ Twi, float4* __restrict__ bt) {
  if (blockIdx.x == gridDim.x - 1) {  // bias block
    const float delta = 0.05f * __uint_as_float(mx[1]);
    const float s = *bscale;
    for (int i = threadIdx.x; i < nb4; i += blockDim.x) {
      float4 v = b4[i];
      float4 o;
      o.x = v.x > delta ? s : (v.x < -delta ? -s : 0.f);
      o.y = v.y > delta ? s : (v.y < -delta ? -s : 0.f);
      o.z = v.z > delta ? s : (v.z < -delta ? -s : 0.f);
      o.w = v.w > delta ? s : (v.w < -delta ? -s : 0.f);
      bt[i] = o;
    }
    return;
  }
  const float delta = 0.05f * __uint_as_float(mx[0]);
  const long stride = (long)(gridDim.x - 1) * blockDim.x;
  for (long i = blockIdx.x * (long)blockDim.x + threadIdx.x; i < nW4; i += stride) {
    float4 w = W4[i];
    int b0 = w.x > delta ? 1 : (w.x < -delta ? 0xFF : 0);
    int b1 = w.y > delta ? 1 : (w.y < -delta ? 0xFF : 0);
    int b2 = w.z > delta ? 1 : (w.z < -delta ? 0xFF : 0);
    int b3 = w.w > delta ? 1 : (w.w < -delta ? 0xFF : 0);
    Twi[i] = b0 | (b1 << 8) | (b2 << 16) | (b3 << 24);
  }
}

// ---------- GEMM: C[m,n] = ws*sx[m]*(sum_k Aq[m,k]*T[n,k]) + bt[n], exact i32 acc ----
// 256x128 tile, 4 waves (2Mx2N), wave tile 128x64 via 4x2x2 grid of 32x32x32 i8
// MFMAs. 256-thread blocks so TWO independent blocks co-reside per CU (unified-file
// budget: ~128 AGPR acc + ~90 VGPR ~= 220 <= 256 -> 2 waves/SIMD): no shared
// barrier between the blocks -> natural anti-phase, one block's MFMA burst covers
// the other's LDS/lgkm phase (the 512-thread single-block version was fully
// serialized: LDS wall + MFMA wall ADDED).
// Swizzle extended with row bit 4: S(r) = ((r>>1)&3) ^ (((r>>4)&1)<<1) -- fixes the
// R3 bank conflicts (lanes 16 apart hit the same bank quartet when only (r>>1)&3
// enters the XOR; adding bit 4 puts lanes {l,l+16,l+32,l+48} in 4 disjoint quartets).
// Ring-3 LDS, prefetch distance 2, counted vmcnt(6) per step (6 gload/wave/step);
// never drained to 0 in the main loop.
__global__ __launch_bounds__(256, 2) void gemm_tern_i8(
    const signed char* __restrict__ A,   // [M,K] i8 quantized x
    const signed char* __restrict__ B,   // [N,K] i8 ternary {-1,0,1}
    const float* __restrict__ sx,        // [M] per-row x scale
    const float* __restrict__ bt,        // [N]
    const float* __restrict__ wsc,       // scalar
    float* __restrict__ C,               // [M,N] fp32
    int M, int N, int K) {
  __shared__ __align__(16) signed char lds[NRING * SLOT];  // 72 KB

  const int tid = threadIdx.x;
  const int wave = tid >> 6;
  const int lane = tid & 63;
  const int wm = wave >> 1, wn = wave & 1;  // 2 x 2 wave grid
  const int l32 = lane & 31;
  const int khalf = lane >> 5;  // 0..1 -> 16B k-chunk within k-sub

  // XCD-aware bijective swizzle: 1024 wgs, 8 XCDs -> each XCD a 4-row M-band,
  // column-major inside (A-panels L2-resident per XCD; B via L3).
  const unsigned orig = blockIdx.x;
  const unsigned xcd = orig & 7;
  const unsigned r8 = orig >> 3;            // 0..127
  const int by = (int)(xcd * 4 + (r8 & 3)); // 0..31  (M)
  const int bx = (int)(r8 >> 2);            // 0..31  (N)
  const int bm0 = by * BM;
  const int bn0 = bx * BN;

  // staging: A = 1024 chunks (idx = j*256+tid, j<4), B = 512 chunks (j<2).
  // row = idx>>2; global chunk = (idx&3) ^ S(row), S in idx-form below.
  const signed char* gA[4];
  const signed char* gB[2];
#pragma unroll
  for (int j = 0; j < 4; ++j) {
    const int idx = j * 256 + tid;
    const int row = idx >> 2;
    const int gch = (idx & 3) ^ ((idx >> 3) & 3) ^ (((idx >> 6) & 1) << 1);
    gA[j] = A + (size_t)(bm0 + row) * K + gch * 16;
    if (j < 2) gB[j] = B + (size_t)(bn0 + row) * K + gch * 16;
  }
  const int wbase = wave * 1024;  // wave-uniform; HW adds lane*16

#define STAGE(wo)                                    \
  do {                                               \
    signed char* l = lds + (wo) + wbase;             \
    GLOAD_LDS(gA[0], l);                             \
    GLOAD_LDS(gA[1], l + 4096);                      \
    GLOAD_LDS(gA[2], l + 8192);                      \
    GLOAD_LDS(gA[3], l + 12288);                     \
    GLOAD_LDS(gB[0], l + 16384);                     \
    GLOAD_LDS(gB[1], l + 20480);                     \
    gA[0] += BKB; gA[1] += BKB; gA[2] += BKB;        \
    gA[3] += BKB; gB[0] += BKB; gB[1] += BKB;        \
  } while (0)

  // fragment addressing: lane reads row = tilebase + l32; global chunk
  // c = khalf + 2*ksub -> LDS pos = c ^ S(row); S(row) == S(l32) since tile
  // bases are multiples of 32.
  const int swzr = ((l32 >> 1) & 3) ^ (((l32 >> 4) & 1) << 1);
  const int pos0 = khalf ^ swzr;   // ksub 0
  const int pos1 = pos0 ^ 2;       // ksub 1  (khalf+2 == khalf^2)
  const int arow = (wm * 128 + l32) * BKB;
  const int brow = BM * BKB + (wn * 64 + l32) * BKB;
  const int aoff0 = arow + pos0 * 16, aoff1 = arow + pos1 * 16;  // + mt*2048
  const int boff0 = brow + pos0 * 16, boff1 = brow + pos1 * 16;  // + nt*2048

  v16i acc[4][2] = {};

#define BODY(ro)                                                                       \
  do {                                                                                 \
    const signed char* s_ = lds + (ro);                                                \
    v4i af_[4][2], bf_[2][2];                                                          \
    _Pragma("unroll")                                                                  \
    for (int mt = 0; mt < 4; ++mt) {                                                   \
      af_[mt][0] = *(const v4i*)(s_ + aoff0 + mt * 2048);                              \
      af_[mt][1] = *(const v4i*)(s_ + aoff1 + mt * 2048);                              \
    }                                                                                  \
    _Pragma("unroll")                                                                  \
    for (int nt = 0; nt < 2; ++nt) {                                                   \
      bf_[nt][0] = *(const v4i*)(s_ + boff0 + nt * 2048);                              \
      bf_[nt][1] = *(const v4i*)(s_ + boff1 + nt * 2048);                              \
    }                                                                                  \
    __builtin_amdgcn_s_setprio(1);                                                     \
    _Pragma("unroll")                                                                  \
    for (int mt = 0; mt < 4; ++mt)                                                     \
      _Pragma("unroll")                                                                \
      for (int nt = 0; nt < 2; ++nt) {                                                 \
        acc[mt][nt] = __builtin_amdgcn_mfma_i32_32x32x32_i8(af_[mt][0], bf_[nt][0],    \
                                                            acc[mt][nt], 0, 0, 0);    \
        acc[mt][nt] = __builtin_amdgcn_mfma_i32_32x32x32_i8(af_[mt][1], bf_[nt][1],    \
                                                            acc[mt][nt], 0, 0, 0);    \
      }                                                                                \
    __builtin_amdgcn_s_setprio(0);                                                     \
  } while (0)

  const int NT = K / BKB;  // 64

  // prologue: stage k-steps 0,1 into slots 0,1
  STAGE(0);
  STAGE(SLOT);
  asm volatile("s_waitcnt vmcnt(6)" ::: "memory");  // stage-0 landed
  asm volatile("s_barrier" ::: "memory");

  int ro = 0;
  int wo = 2 * SLOT;
  // main loop: stage t+2, compute t. vmcnt(6) before barrier => after barrier all
  // waves' stage-(t+1) landed (in-flight <= the 6 loads of stage-(t+2)).
  for (int t = 0; t < NT - 2; ++t) {
    STAGE(wo);
    wo = (wo == 2 * SLOT) ? 0 : wo + SLOT;
    BODY(ro);
    asm volatile("s_waitcnt vmcnt(6)" ::: "memory");
    asm volatile("s_barrier" ::: "memory");
    ro = (ro == 2 * SLOT) ? 0 : ro + SLOT;
  }
  // tail: step NT-2 (stage NT-1 still in flight), then drain, then step NT-1
  BODY(ro);
  ro = (ro == 2 * SLOT) ? 0 : ro + SLOT;
  asm volatile("s_waitcnt vmcnt(0)" ::: "memory");
  asm volatile("s_barrier" ::: "memory");
  BODY(ro);
#undef BODY
#undef STAGE

  // epilogue: 32x32 D layout col = lane&31, row = (r&3) + 8*(r>>2) + 4*(lane>>5)
  const float ws = *wsc;
#pragma unroll
  for (int mt = 0; mt < 4; ++mt) {
    const int rowbase = bm0 + wm * 128 + mt * 32 + 4 * khalf;
#pragma unroll
    for (int nt = 0; nt < 2; ++nt) {
      const int col = bn0 + wn * 64 + nt * 32 + l32;
      const float bias = bt[col];
#pragma unroll
      for (int r = 0; r < 16; ++r) {
        const int row = rowbase + (r & 3) + 8 * (r >> 2);
        C[(size_t)row * N + col] = ws * sx[row] * (float)acc[mt][nt][r] + bias;
      }
    }
  }
}

// ---------- launch ----------

extern "C" void kernel_launch(void* const* d_in, const int* in_sizes, int n_in,
                              void* d_out, int out_size, void* d_ws, size_t ws_size,
                              hipStream_t stream) {
  const float* x = (const float*)d_in[0];
  const float* W = (const float*)d_in[1];
  const float* w_scale = (const float*)d_in[2];
  const float* b = (const float*)d_in[3];
  const float* b_scale = (const float*)d_in[4];
  float* out = (float*)d_out;

  const int K = 4096;             // D_IN
  const int N = in_sizes[3];      // D_OUT = 4096
  const int M = in_sizes[0] / K;  // B*S = 8192

  // workspace layout
  char* ws = (char*)d_ws;
  signed char* xb = (signed char*)ws;                        // M*K i8 (32 MB)
  signed char* Tw = (signed char*)(ws + (size_t)M * K);      // N*K i8 (16 MB)
  float* bt = (float*)(ws + (size_t)M * K + (size_t)N * K);  // N fp32
  float* sx = bt + N;                                        // M fp32
  unsigned* mx = (unsigned*)(sx + M);                        // [0]=max|W|,[1]=max|b|

  hipMemsetAsync(mx, 0, 8, stream);

  const long nW4 = (long)N * K / 4;
  const int nb4 = N / 4;

  // fused xquant + absmax(W) + absmax(b): 8192 + 1024 + 1 blocks
  prep1_kernel<<<M + 1024 + 1, 256, 0, stream>>>((const float4*)x, xb, sx, K, M,
                                                 (const float4*)W, nW4,
                                                 (const float4*)b, nb4, mx);

  prep_w_kernel<<<2049, 256, 0, stream>>>((const float4*)W, nW4,
                                          (const float4*)b, nb4, mx, b_scale,
                                          (int*)Tw, (float4*)bt);

  const int nwg = (N / BN) * (M / BM);  // 32 * 32 = 1024, divisible by 8
  gemm_tern_i8<<<nwg, 256, 0, stream>>>(xb, Tw, sx, bt, w_scale, out, M, N, K);
}

// Round 6
// 398.631 us; speedup vs baseline: 1.0476x; 1.0476x over previous
//
#include <hip/hip_runtime.h>

typedef int v4i __attribute__((ext_vector_type(4)));

#define BM 256
#define BN 256
#define BKB 64   // K-bytes per LDS slot row step (i8). 64 B rows.
#define NRING 4  // 4 slots x (16KB A + 16KB B) = 128 KB LDS, prefetch distance 3

// async global->LDS, 16B per lane. LDS dest = wave-uniform base + lane*16.
#define GLOAD_LDS(gptr, lptr)                                                         \
  __builtin_amdgcn_global_load_lds(                                                   \
      (const __attribute__((address_space(1))) unsigned int*)(gptr),                  \
      (__attribute__((address_space(3))) unsigned int*)(lptr), 16, 0, 0)

// ---------- preprocessing ----------

__device__ __forceinline__ float max4abs(float4 v) {
  return fmaxf(fmaxf(fabsf(v.x), fabsf(v.y)), fmaxf(fabsf(v.z), fabsf(v.w)));
}

__device__ __forceinline__ int packq4(float4 v, float inv) {
  int b0 = ((int)fminf(127.f, fmaxf(-127.f, rintf(v.x * inv)))) & 255;
  int b1 = ((int)fminf(127.f, fmaxf(-127.f, rintf(v.y * inv)))) & 255;
  int b2 = ((int)fminf(127.f, fmaxf(-127.f, rintf(v.z * inv)))) & 255;
  int b3 = ((int)fminf(127.f, fmaxf(-127.f, rintf(v.w * inv)))) & 255;
  return b0 | (b1 << 8) | (b2 << 16) | (b3 << 24);
}

// Fused: blocks [0,nrows) per-row i8-quantize x; blocks [nrows,nrows+1024) reduce
// max|W|; last block reduces max|b|. All independent -> one dispatch.
__global__ void prep1_kernel(const float4* __restrict__ X4,
                             signed char* __restrict__ Q,
                             float* __restrict__ sx, int K, int nrows,
                             const float4* __restrict__ W4, long nW4,
                             const float4* __restrict__ b4, int nb4,
                             unsigned* __restrict__ mx) {
  __shared__ float sm[4];
  const int tid = threadIdx.x;
  const int bid = blockIdx.x;

  if (bid < nrows) {  // ---- xquant: one block per row, K==4096 assumed
    const float4* xr = X4 + (size_t)bid * (K / 4);
    float4 v0 = xr[tid], v1 = xr[tid + 256], v2 = xr[tid + 512], v3 = xr[tid + 768];
    float m = fmaxf(fmaxf(max4abs(v0), max4abs(v1)), fmaxf(max4abs(v2), max4abs(v3)));
    for (int off = 32; off > 0; off >>= 1) m = fmaxf(m, __shfl_down(m, off));
    if ((tid & 63) == 0) sm[tid >> 6] = m;
    __syncthreads();
    const float total = fmaxf(fmaxf(sm[0], sm[1]), fmaxf(sm[2], sm[3]));
    const float inv = 127.f / total;
    int* qw = (int*)(Q + (size_t)bid * K);
    qw[tid]       = packq4(v0, inv);
    qw[tid + 256] = packq4(v1, inv);
    qw[tid + 512] = packq4(v2, inv);
    qw[tid + 768] = packq4(v3, inv);
    if (tid == 0) sx[bid] = total * (1.f / 127.f);
    return;
  }

  // ---- absmax reductions
  float m = 0.f;
  const bool isB = (bid == gridDim.x - 1);
  if (!isB) {
    const long wb = bid - nrows;           // 0..1023
    const long stride = 1024L * blockDim.x;
    for (long i = wb * blockDim.x + tid; i < nW4; i += stride)
      m = fmaxf(m, max4abs(W4[i]));
  } else {
    for (int i = tid; i < nb4; i += blockDim.x) m = fmaxf(m, max4abs(b4[i]));
  }
  for (int off = 32; off > 0; off >>= 1) m = fmaxf(m, __shfl_down(m, off));
  if ((tid & 63) == 0) sm[tid >> 6] = m;
  __syncthreads();
  if (tid == 0) {
    m = fmaxf(fmaxf(sm[0], sm[1]), fmaxf(sm[2], sm[3]));
    atomicMax(mx + (isB ? 1 : 0), __float_as_uint(m));  // nonneg: uint order == float
  }
}

// Ternarize W -> i8{-1,0,1} (packed dword per float4, coalesced); last block: b -> fp32.
__global__ void prep_w_kernel(const float4* __restrict__ W4, long nW4,
                              const float4* __restrict__ b4, int nb4,
                              const unsigned* __restrict__ mx,
                              const float* __restrict__ bscale,
                              int* __restrict__ Twi, float4* __restrict__ bt) {
  if (blockIdx.x == gridDim.x - 1) {  // bias block
    const float delta = 0.05f * __uint_as_float(mx[1]);
    const float s = *bscale;
    for (int i = threadIdx.x; i < nb4; i += blockDim.x) {
      float4 v = b4[i];
      float4 o;
      o.x = v.x > delta ? s : (v.x < -delta ? -s : 0.f);
      o.y = v.y > delta ? s : (v.y < -delta ? -s : 0.f);
      o.z = v.z > delta ? s : (v.z < -delta ? -s : 0.f);
      o.w = v.w > delta ? s : (v.w < -delta ? -s : 0.f);
      bt[i] = o;
    }
    return;
  }
  const float delta = 0.05f * __uint_as_float(mx[0]);
  const long stride = (long)(gridDim.x - 1) * blockDim.x;
  for (long i = blockIdx.x * (long)blockDim.x + threadIdx.x; i < nW4; i += stride) {
    float4 w = W4[i];
    int b0 = w.x > delta ? 1 : (w.x < -delta ? 0xFF : 0);
    int b1 = w.y > delta ? 1 : (w.y < -delta ? 0xFF : 0);
    int b2 = w.z > delta ? 1 : (w.z < -delta ? 0xFF : 0);
    int b3 = w.w > delta ? 1 : (w.w < -delta ? 0xFF : 0);
    Twi[i] = b0 | (b1 << 8) | (b2 << 16) | (b3 << 24);
  }
}

// ---------- GEMM: C[m,n] = ws*sx[m]*(sum_k Aq[m,k]*T[n,k]) + bt[n], exact i32 acc ----
// R1 champion geometry (verified: 0 bank conflicts, 138.5us): 256x256 tile, 8 waves
// (2Mx4N), wave tile 128x64 via 8x4 grid of 16x16x64 i8 MFMAs, ring-4 LDS, XCD
// swizzle. NEW: register-level cross-batch pipeline. The 32 MFMA/step are split
// along mt into two 16-MFMA batches (afA=mt0-3, afB=mt4-7, shared bf); between
// batches we issue the NEXT batch's ds_reads, so each MFMA batch overlaps a read
// stream (R1 measured 2597 cyc/step == LDS wall + MFMA wall SUMMED; target max()).
// bf ping-pongs P/Q across steps (+16 VGPR). Reading slot t+1 mid-step is licensed
// by vmcnt(4): at every barrier, outstanding <= 4 (= newest stage) => stage(t+2)
// retired => slots t+1, t+2 resident after the end-of-t barrier. sched_group_barrier
// pins the read/MFMA interleave; setprio(1) around MFMA batches (T5: phases exist now).
__global__ __launch_bounds__(512, 2) void gemm_tern_i8(
    const signed char* __restrict__ A,   // [M,K] i8 quantized x
    const signed char* __restrict__ B,   // [N,K] i8 ternary {-1,0,1}
    const float* __restrict__ sx,        // [M] per-row x scale
    const float* __restrict__ bt,        // [N]
    const float* __restrict__ wsc,       // scalar
    float* __restrict__ C,               // [M,N] fp32
    int M, int N, int K) {
  __shared__ __align__(16) signed char lds[NRING][2][BM * BKB];  // 128 KB

  const int tid = threadIdx.x;
  const int wave = tid >> 6;
  const int lane = tid & 63;
  const int wm = wave >> 2, wn = wave & 3;  // 2 x 4 wave grid
  const int quad = lane >> 4;               // 0..3
  const int l16 = lane & 15;

  // XCD-aware bijective swizzle: 512 wgs, 8 XCDs -> 4-M-row band each, col-major
  // inside (kept from R2: FETCH 147->98 MB).
  const unsigned orig = blockIdx.x;
  const unsigned xcd = orig & 7;
  const unsigned r8 = orig >> 3;            // 0..63
  const int by = (int)(xcd * 4 + (r8 & 3)); // 0..31  (M)
  const int bx = (int)(r8 >> 2);            // 0..15  (N)
  const int bm0 = by * BM;
  const int bn0 = bx * BN;

  // staging: 1024 16B-chunks per matrix per tile; thread covers idx = j*512 + tid.
  // row = idx>>2, global chunk = (idx&3) ^ ((row>>1)&3) = (idx&3) ^ ((idx>>3)&3).
  const signed char *gA0, *gA1, *gB0, *gB1;
  {
    const int i0 = tid, i1 = 512 + tid;
    const int r0 = i0 >> 2, r1 = i1 >> 2;
    const int c0 = (i0 & 3) ^ ((i0 >> 3) & 3);
    const int c1 = (i1 & 3) ^ ((i1 >> 3) & 3);
    gA0 = A + (size_t)(bm0 + r0) * K + c0 * 16;
    gA1 = A + (size_t)(bm0 + r1) * K + c1 * 16;
    gB0 = B + (size_t)(bn0 + r0) * K + c0 * 16;
    gB1 = B + (size_t)(bn0 + r1) * K + c1 * 16;
  }
  const int ldsbase = wave * 64 * 16;  // wave-uniform; HW adds lane*16

#define STAGE(slot)                                  \
  do {                                               \
    signed char* la = &lds[slot][0][ldsbase];        \
    signed char* lb = &lds[slot][1][ldsbase];        \
    GLOAD_LDS(gA0, la);                              \
    GLOAD_LDS(gA1, la + 8192);                       \
    GLOAD_LDS(gB0, lb);                              \
    GLOAD_LDS(gB1, lb + 8192);                       \
    gA0 += BKB; gA1 += BKB; gB0 += BKB; gB1 += BKB;  \
  } while (0)

  // fragment: row = wm*128 + mt*16 + l16, swizzled 16B k-chunk (verified 0-conflict).
  const int kchunk = quad ^ ((l16 >> 1) & 3);
  const int aoff = (wm * 128 + l16) * BKB + kchunk * 16;  // + mt*1024
  const int boff = (wn * 64 + l16) * BKB + kchunk * 16;   // + nt*1024

  v4i afA[4], afB[4], bfP[4], bfQ[4];
  v4i acc[8][4] = {};

#define RD_AFA(T)                                         \
  do {                                                    \
    const signed char* s_ = &lds[(T) & 3][0][0];          \
    afA[0] = *(const v4i*)(s_ + aoff);                    \
    afA[1] = *(const v4i*)(s_ + aoff + 1024);             \
    afA[2] = *(const v4i*)(s_ + aoff + 2048);             \
    afA[3] = *(const v4i*)(s_ + aoff + 3072);             \
  } while (0)
#define RD_AFB(T)                                         \
  do {                                                    \
    const signed char* s_ = &lds[(T) & 3][0][0];          \
    afB[0] = *(const v4i*)(s_ + aoff + 4096);             \
    afB[1] = *(const v4i*)(s_ + aoff + 5120);             \
    afB[2] = *(const v4i*)(s_ + aoff + 6144);             \
    afB[3] = *(const v4i*)(s_ + aoff + 7168);             \
  } while (0)
#define RD_BF(DST, T)                                     \
  do {                                                    \
    const signed char* s_ = &lds[(T) & 3][1][0];          \
    DST[0] = *(const v4i*)(s_ + boff);                    \
    DST[1] = *(const v4i*)(s_ + boff + 1024);             \
    DST[2] = *(const v4i*)(s_ + boff + 2048);             \
    DST[3] = *(const v4i*)(s_ + boff + 3072);             \
  } while (0)

#define MM(AF, BF, MB)                                                        \
  do {                                                                        \
    __builtin_amdgcn_s_setprio(1);                                            \
    _Pragma("unroll")                                                         \
    for (int mt = 0; mt < 4; ++mt)                                            \
      _Pragma("unroll")                                                       \
      for (int nt = 0; nt < 4; ++nt)                                          \
        acc[(MB) + mt][nt] = __builtin_amdgcn_mfma_i32_16x16x64_i8(           \
            AF[mt], BF[nt], acc[(MB) + mt][nt], 0, 0, 0);                     \
    __builtin_amdgcn_s_setprio(0);                                            \
  } while (0)

#define SGB(m, n) __builtin_amdgcn_sched_group_barrier((m), (n), 0)
// per-half-step interleave spec: stage(4 vmem) | 4 ds | 16 mfma | 8 ds | 16 mfma
#define PIN_FULL() do { SGB(0x20,4); SGB(0x100,4); SGB(0x8,16); SGB(0x100,8); SGB(0x8,16); } while (0)
#define PIN_NOST() do { SGB(0x100,4); SGB(0x8,16); SGB(0x100,8); SGB(0x8,16); } while (0)

#define VMB(n)                                            \
  do {                                                    \
    asm volatile("s_waitcnt vmcnt(" #n ")" ::: "memory"); \
    asm volatile("s_barrier" ::: "memory");               \
  } while (0)

  // ---- prologue: stage slots 0,1,2; slots 0,1 resident after vmcnt(4)
  STAGE(0); STAGE(1); STAGE(2);
  asm volatile("s_waitcnt vmcnt(4)" ::: "memory");
  asm volatile("s_barrier" ::: "memory");
  RD_AFA(0);
  RD_BF(bfP, 0);

  // ---- main loop: steps 0..59 (NT==64 assumed, K==4096); stage t+3 each step
  for (int t = 0; t < 60; t += 2) {
    // step t (even): current bf = bfP
    STAGE((t + 3) & 3);
    RD_AFB(t);
    MM(afA, bfP, 0);
    RD_AFA(t + 1);
    RD_BF(bfQ, t + 1);
    MM(afB, bfP, 4);
    PIN_FULL();
    VMB(4);
    // step t+1 (odd): current bf = bfQ
    STAGE((t + 4) & 3);
    RD_AFB(t + 1);
    MM(afA, bfQ, 0);
    RD_AFA(t + 2);
    RD_BF(bfP, t + 2);
    MM(afB, bfQ, 4);
    PIN_FULL();
    VMB(4);
  }
  // ---- peeled steps 60..63
  // step 60 (bfP): stages slot 63 (last stage)
  STAGE(3);
  RD_AFB(60);
  MM(afA, bfP, 0);
  RD_AFA(61);
  RD_BF(bfQ, 61);
  MM(afB, bfP, 4);
  PIN_FULL();
  VMB(4);
  // step 61 (bfQ): drain to 0 -> slot 63 resident for all waves after barrier
  RD_AFB(61);
  MM(afA, bfQ, 0);
  RD_AFA(62);
  RD_BF(bfP, 62);
  MM(afB, bfQ, 4);
  PIN_NOST();
  VMB(0);
  // step 62 (bfP): no further LDS writes -> no more barriers needed
  RD_AFB(62);
  MM(afA, bfP, 0);
  RD_AFA(63);
  RD_BF(bfQ, 63);
  MM(afB, bfP, 4);
  // step 63 (bfQ)
  RD_AFB(63);
  MM(afA, bfQ, 0);
  MM(afB, bfQ, 4);

#undef STAGE
#undef RD_AFA
#undef RD_AFB
#undef RD_BF
#undef MM
#undef SGB
#undef PIN_FULL
#undef PIN_NOST
#undef VMB

  // epilogue: D layout col=lane&15, row=quad*4+reg (shape-determined, dtype-indep)
  const float ws = *wsc;
#pragma unroll
  for (int mt = 0; mt < 8; ++mt) {
    const int row = bm0 + wm * 128 + mt * 16 + quad * 4;
    float sc[4];
#pragma unroll
    for (int r = 0; r < 4; ++r) sc[r] = ws * sx[row + r];
#pragma unroll
    for (int nt = 0; nt < 4; ++nt) {
      const int col = bn0 + wn * 64 + nt * 16 + l16;
      const float bias = bt[col];
#pragma unroll
      for (int r = 0; r < 4; ++r)
        C[(size_t)(row + r) * N + col] = sc[r] * (float)acc[mt][nt][r] + bias;
    }
  }
}

// ---------- launch ----------

extern "C" void kernel_launch(void* const* d_in, const int* in_sizes, int n_in,
                              void* d_out, int out_size, void* d_ws, size_t ws_size,
                              hipStream_t stream) {
  const float* x = (const float*)d_in[0];
  const float* W = (const float*)d_in[1];
  const float* w_scale = (const float*)d_in[2];
  const float* b = (const float*)d_in[3];
  const float* b_scale = (const float*)d_in[4];
  float* out = (float*)d_out;

  const int K = 4096;             // D_IN
  const int N = in_sizes[3];      // D_OUT = 4096
  const int M = in_sizes[0] / K;  // B*S = 8192

  // workspace layout
  char* ws = (char*)d_ws;
  signed char* xb = (signed char*)ws;                        // M*K i8 (32 MB)
  signed char* Tw = (signed char*)(ws + (size_t)M * K);      // N*K i8 (16 MB)
  float* bt = (float*)(ws + (size_t)M * K + (size_t)N * K);  // N fp32
  float* sx = bt + N;                                        // M fp32
  unsigned* mx = (unsigned*)(sx + M);                        // [0]=max|W|,[1]=max|b|

  hipMemsetAsync(mx, 0, 8, stream);

  const long nW4 = (long)N * K / 4;
  const int nb4 = N / 4;

  // fused xquant + absmax(W) + absmax(b): 8192 + 1024 + 1 blocks
  prep1_kernel<<<M + 1024 + 1, 256, 0, stream>>>((const float4*)x, xb, sx, K, M,
                                                 (const float4*)W, nW4,
                                                 (const float4*)b, nb4, mx);

  prep_w_kernel<<<2049, 256, 0, stream>>>((const float4*)W, nW4,
                                          (const float4*)b, nb4, mx, b_scale,
                                          (int*)Tw, (float4*)bt);

  const int nwg = (N / BN) * (M / BM);  // 16 * 32 = 512, divisible by 8
  gemm_tern_i8<<<nwg, 512, 0, stream>>>(xb, Tw, sx, bt, w_scale, out, M, N, K);
}